// Round 2
// baseline (1148.220 us; speedup 1.0000x reference)
//
#include <hip/hip_runtime.h>

#define NN 100000
#define EE 250000
#define DD 128

// ---------------- degree kernels ----------------
__global__ __launch_bounds__(256) void k_init_deg(float* __restrict__ deg) {
    int i = blockIdx.x * 256 + threadIdx.x;
    if (i < NN) deg[i] = 1.0f;
}

__global__ __launch_bounds__(256) void k_deg(const int* __restrict__ ei, float* __restrict__ deg) {
    int e = blockIdx.x * 256 + threadIdx.x;
    if (e < EE) {
        unsafeAtomicAdd(&deg[ei[e]], 1.0f);        // HW global_atomic_add_f32
        unsafeAtomicAdd(&deg[ei[EE + e]], 1.0f);
    }
}

__global__ __launch_bounds__(256) void k_rsqrt(float* __restrict__ deg) {
    int i = blockIdx.x * 256 + threadIdx.x;
    if (i < NN) deg[i] = rsqrtf(deg[i]);   // deg >= 1, clip(…,1e-12) is dead
}

// ---------------- GEMM: h = x @ W^T + b ----------------
// Block: 256 threads, 64 rows of x, all 128 output cols.
// W staged in LDS with +1 pad (129-float stride -> 2-way bank alias = free).
// Thread t: col = t&127, rows rb..rb+31 (rb = (t>>7)*32). 32 accumulators.
// LDS total 98816 B (<160 KiB/CU, gfx950 allows >64KB static — cf. the
// 128 KiB 8-phase GEMM template).
__global__ __launch_bounds__(256) void k_gemm(const float* __restrict__ x,
                                              const float* __restrict__ W,
                                              const float* __restrict__ bias,
                                              float* __restrict__ h) {
    __shared__ float Ws[DD][DD + 1];   // 66048 B
    __shared__ float xs[64][DD];       // 32768 B
    const int t = threadIdx.x;
    const int row0 = blockIdx.x * 64;

    // Load W (128x128 fp32) cooperatively, float4 global reads.
    for (int i = t; i < DD * DD / 4; i += 256) {
        float4 w4 = ((const float4*)W)[i];
        int base = i * 4;
        int r = base >> 7, c = base & 127;
        Ws[r][c] = w4.x; Ws[r][c + 1] = w4.y; Ws[r][c + 2] = w4.z; Ws[r][c + 3] = w4.w;
    }
    // Load x tile (64x128), zero-pad past N.
    for (int i = t; i < 64 * DD / 4; i += 256) {
        int base = i * 4;
        int r = base >> 7, c = base & 127;
        float4 v;
        if (row0 + r < NN) v = ((const float4*)(x + (size_t)(row0 + r) * DD))[c >> 2];
        else               v = make_float4(0.f, 0.f, 0.f, 0.f);
        xs[r][c] = v.x; xs[r][c + 1] = v.y; xs[r][c + 2] = v.z; xs[r][c + 3] = v.w;
    }
    __syncthreads();

    const int col = t & 127;
    const int rb  = (t >> 7) << 5;   // 0 or 32
    float acc[32];
    #pragma unroll
    for (int r = 0; r < 32; r++) acc[r] = 0.f;

    for (int k = 0; k < DD; k += 4) {
        float w0 = Ws[col][k], w1 = Ws[col][k + 1], w2 = Ws[col][k + 2], w3 = Ws[col][k + 3];
        #pragma unroll
        for (int r = 0; r < 32; r++) {
            float4 xv = *(const float4*)&xs[rb + r][k];   // wave-broadcast b128 read
            acc[r] = fmaf(xv.x, w0, acc[r]);
            acc[r] = fmaf(xv.y, w1, acc[r]);
            acc[r] = fmaf(xv.z, w2, acc[r]);
            acc[r] = fmaf(xv.w, w3, acc[r]);
        }
    }
    float bv = bias[col];
    #pragma unroll
    for (int r = 0; r < 32; r++) {
        int row = row0 + rb + r;
        if (row < NN) h[(size_t)row * DD + col] = acc[r] + bv;
    }
}

// ---------------- self-loop init: out[i] = h[i] * r[i]^2 ----------------
// Also overwrites the harness's 0xAA poison in d_out.
__global__ __launch_bounds__(256) void k_self(const float* __restrict__ h,
                                              const float* __restrict__ r,
                                              float* __restrict__ out) {
    long long i = (long long)blockIdx.x * 256 + threadIdx.x;   // NN*32 float4 slots
    if (i >= (long long)NN * 32) return;
    int node = (int)(i >> 5);
    int lane = (int)(i & 31);
    float rv = r[node];
    float c = rv * rv;
    float4 hv = ((const float4*)(h + (size_t)node * DD))[lane];
    ((float4*)(out + (size_t)node * DD))[lane] =
        make_float4(hv.x * c, hv.y * c, hv.z * c, hv.w * c);
}

// ---------------- edge scatter: 32 lanes per directed edge ----------------
__global__ __launch_bounds__(256) void k_scatter(const int* __restrict__ ei,
                                                 const float* __restrict__ h,
                                                 const float* __restrict__ r,
                                                 float* __restrict__ out) {
    long long tid = (long long)blockIdx.x * 256 + threadIdx.x;
    long long gid = tid >> 5;           // directed-edge task id
    int lane = (int)(tid & 31);
    if (gid >= 2LL * EE) return;
    int e   = (int)(gid >> 1);
    int dir = (int)(gid & 1);
    int u = ei[e];
    int v = ei[EE + e];
    int src = dir ? v : u;
    int dst = dir ? u : v;
    float coef = r[src] * r[dst];
    float4 hv = ((const float4*)(h + (size_t)src * DD))[lane];
    float* o = out + (size_t)dst * DD + lane * 4;
    unsafeAtomicAdd(o + 0, hv.x * coef);
    unsafeAtomicAdd(o + 1, hv.y * coef);
    unsafeAtomicAdd(o + 2, hv.z * coef);
    unsafeAtomicAdd(o + 3, hv.w * coef);
}

extern "C" void kernel_launch(void* const* d_in, const int* in_sizes, int n_in,
                              void* d_out, int out_size, void* d_ws, size_t ws_size,
                              hipStream_t stream) {
    const float* x  = (const float*)d_in[0];
    const int*   ei = (const int*)d_in[1];
    const float* W  = (const float*)d_in[2];
    const float* b  = (const float*)d_in[3];
    float* out = (float*)d_out;

    float* h   = (float*)d_ws;                 // N*128 fp32 = 51.2 MB
    float* deg = h + (size_t)NN * DD;          // N fp32 (becomes rsqrt(deg) in place)

    k_init_deg<<<(NN + 255) / 256, 256, 0, stream>>>(deg);
    k_deg<<<(EE + 255) / 256, 256, 0, stream>>>(ei, deg);
    k_rsqrt<<<(NN + 255) / 256, 256, 0, stream>>>(deg);
    k_gemm<<<(NN + 63) / 64, 256, 0, stream>>>(x, W, b, h);
    k_self<<<(NN * 32 + 255) / 256, 256, 0, stream>>>(h, deg, out);
    k_scatter<<<(2 * EE * 32 + 255) / 256, 256, 0, stream>>>(ei, h, deg, out);
}

// Round 3
// 324.023 us; speedup vs baseline: 3.5436x; 3.5436x over previous
//
#include <hip/hip_runtime.h>

#define NN 100000
#define EE 250000
#define DD 128
#define NB_SCAN 98   // ceil(NN/1024)

// ---------------- CSR build ----------------
__global__ __launch_bounds__(256) void k_zero(int* __restrict__ cnt) {
    int i = blockIdx.x * 256 + threadIdx.x;
    if (i < NN) cnt[i] = 0;
}

__global__ __launch_bounds__(256) void k_count(const int* __restrict__ ei, int* __restrict__ cnt) {
    int e = blockIdx.x * 256 + threadIdx.x;
    if (e < EE) {
        atomicAdd(&cnt[ei[e]], 1);        // directed v->u lands at dst=u ... symmetric:
        atomicAdd(&cnt[ei[EE + e]], 1);   // in-degree over directed edges == undirected degree
    }
}

__global__ __launch_bounds__(256) void k_r(const int* __restrict__ cnt, float* __restrict__ r) {
    int i = blockIdx.x * 256 + threadIdx.x;
    if (i < NN) r[i] = rsqrtf((float)cnt[i] + 1.0f);   // deg>=1 -> clip dead
}

__global__ __launch_bounds__(1024) void k_scan1(const int* __restrict__ cnt,
                                                int* __restrict__ offs, int* __restrict__ bsum) {
    __shared__ int s[1024];
    int gid = blockIdx.x * 1024 + threadIdx.x;
    int v = (gid < NN) ? cnt[gid] : 0;
    s[threadIdx.x] = v;
    __syncthreads();
    for (int d = 1; d < 1024; d <<= 1) {            // Hillis-Steele inclusive scan
        int t = (threadIdx.x >= d) ? s[threadIdx.x - d] : 0;
        __syncthreads();
        s[threadIdx.x] += t;
        __syncthreads();
    }
    if (gid < NN) offs[gid] = s[threadIdx.x] - v;   // exclusive
    if (threadIdx.x == 1023) bsum[blockIdx.x] = s[1023];
}

__global__ void k_scan2(int* __restrict__ bsum) {   // 1 thread, 98 elems: serial exclusive scan
    if (threadIdx.x == 0 && blockIdx.x == 0) {
        int run = 0;
        for (int i = 0; i < NB_SCAN; i++) { int v = bsum[i]; bsum[i] = run; run += v; }
    }
}

__global__ __launch_bounds__(1024) void k_scan3(int* __restrict__ offs, const int* __restrict__ bsum,
                                                int* __restrict__ cursor) {
    int gid = blockIdx.x * 1024 + threadIdx.x;
    if (gid < NN) {
        int o = offs[gid] + bsum[blockIdx.x];
        offs[gid] = o;
        cursor[gid] = o;
    }
}

__global__ __launch_bounds__(256) void k_fill(const int* __restrict__ ei,
                                              int* __restrict__ cursor, int* __restrict__ bucket) {
    int e = blockIdx.x * 256 + threadIdx.x;
    if (e < EE) {
        int u = ei[e], v = ei[EE + e];
        bucket[atomicAdd(&cursor[v], 1)] = u;   // edge u->v : src u into dst-v's list
        bucket[atomicAdd(&cursor[u], 1)] = v;   // edge v->u : src v into dst-u's list
    }
}

// ---------------- GEMM: h = x @ W^T + b ----------------
// 128x128 output block, 256 threads (16x16), 8x8 register micro-tile in
// split-4 form (rows ty*4+i and 64+ty*4+i; cols tx*4+j and 64+tx*4+j).
// Both tiles row-major in LDS, K contiguous -> dot-product micro-kernel,
// no transpose staging. Pad 132 floats (528 B): float4-aligned, banks:
// a-reads 2-way (free), b-reads 2-way (free). 256 FMA : 16 ds_read_b128.
__global__ __launch_bounds__(256) void k_gemm(const float* __restrict__ x,
                                              const float* __restrict__ W,
                                              const float* __restrict__ bias,
                                              float* __restrict__ h) {
    __shared__ float xs[128][132];   // 67584 B
    __shared__ float ws[128][132];   // 67584 B   (total 132 KiB < 160 KiB)
    const int t = threadIdx.x;
    const int row0 = blockIdx.x * 128;

    for (int i = t; i < 4096; i += 256) {          // W: 128x128 floats = 4096 float4
        float4 w4 = ((const float4*)W)[i];
        int r = i >> 5, c = (i & 31) << 2;
        *(float4*)&ws[r][c] = w4;
    }
    for (int i = t; i < 4096; i += 256) {          // x tile, zero-pad past N
        int r = i >> 5, c = (i & 31) << 2;
        float4 v = make_float4(0.f, 0.f, 0.f, 0.f);
        if (row0 + r < NN) v = ((const float4*)(x + (size_t)(row0 + r) * DD))[i & 31];
        *(float4*)&xs[r][c] = v;
    }
    __syncthreads();

    const int tx = t & 15, ty = t >> 4;
    float acc[8][8];
    #pragma unroll
    for (int i = 0; i < 8; i++)
        #pragma unroll
        for (int j = 0; j < 8; j++) acc[i][j] = 0.f;

    #pragma unroll 2
    for (int k = 0; k < DD; k += 4) {
        float4 a[8], b[8];
        #pragma unroll
        for (int i = 0; i < 4; i++) {
            a[i]     = *(const float4*)&xs[ty * 4 + i][k];
            a[4 + i] = *(const float4*)&xs[64 + ty * 4 + i][k];
            b[i]     = *(const float4*)&ws[tx * 4 + i][k];
            b[4 + i] = *(const float4*)&ws[64 + tx * 4 + i][k];
        }
        #pragma unroll
        for (int i = 0; i < 8; i++)
            #pragma unroll
            for (int j = 0; j < 8; j++) {
                acc[i][j] = fmaf(a[i].x, b[j].x, acc[i][j]);
                acc[i][j] = fmaf(a[i].y, b[j].y, acc[i][j]);
                acc[i][j] = fmaf(a[i].z, b[j].z, acc[i][j]);
                acc[i][j] = fmaf(a[i].w, b[j].w, acc[i][j]);
            }
    }

    float4 bv0 = *(const float4*)&bias[tx * 4];
    float4 bv1 = *(const float4*)&bias[64 + tx * 4];
    #pragma unroll
    for (int i = 0; i < 8; i++) {
        int row = row0 + ((i < 4) ? (ty * 4 + i) : (64 + ty * 4 + i - 4));
        if (row < NN) {
            float4 o0 = make_float4(acc[i][0] + bv0.x, acc[i][1] + bv0.y,
                                    acc[i][2] + bv0.z, acc[i][3] + bv0.w);
            float4 o1 = make_float4(acc[i][4] + bv1.x, acc[i][5] + bv1.y,
                                    acc[i][6] + bv1.z, acc[i][7] + bv1.w);
            *(float4*)&h[(size_t)row * DD + tx * 4]      = o0;
            *(float4*)&h[(size_t)row * DD + 64 + tx * 4] = o1;
        }
    }
}

// ---------------- gather: one wave per dst node, no atomics ----------------
// out[n] = h[n]*r[n]^2 + sum_{src in adj(n)} h[src] * r[src]*r[n]
__global__ __launch_bounds__(256) void k_gather(const int* __restrict__ bucket,
                                                const int* __restrict__ offs,
                                                const int* __restrict__ cursor,
                                                const float* __restrict__ h,
                                                const float* __restrict__ r,
                                                float* __restrict__ out) {
    int wid  = (blockIdx.x * 256 + threadIdx.x) >> 6;
    int lane = threadIdx.x & 63;
    if (wid >= NN) return;
    const int node = wid;
    const float rd = r[node];
    const int start = offs[node];
    const int end   = cursor[node];          // == offs[node] + deg  (post-fill)
    float2 acc = ((const float2*)(h + (size_t)node * DD))[lane];
    const float c0 = rd * rd;                // self loop
    acc.x *= c0; acc.y *= c0;
    for (int j = start; j < end; ++j) {
        int src = bucket[j];                 // wave-uniform -> single coalesced request
        float coef = r[src] * rd;
        float2 hv = ((const float2*)(h + (size_t)src * DD))[lane];
        acc.x = fmaf(hv.x, coef, acc.x);
        acc.y = fmaf(hv.y, coef, acc.y);
    }
    ((float2*)(out + (size_t)node * DD))[lane] = acc;
}

extern "C" void kernel_launch(void* const* d_in, const int* in_sizes, int n_in,
                              void* d_out, int out_size, void* d_ws, size_t ws_size,
                              hipStream_t stream) {
    const float* x  = (const float*)d_in[0];
    const int*   ei = (const int*)d_in[1];
    const float* W  = (const float*)d_in[2];
    const float* b  = (const float*)d_in[3];
    float* out = (float*)d_out;

    // workspace layout (4-byte units)
    float* h      = (float*)d_ws;                       // 12.8M floats = 51.2 MB
    float* r      = h + (size_t)NN * DD;                // 100k
    int*   cnt    = (int*)(r + NN);                     // 100k
    int*   offs   = cnt + NN;                           // 100k
    int*   cursor = offs + NN;                          // 100k
    int*   bsum   = cursor + NN;                        // 128
    int*   bucket = bsum + 128;                         // 500k  (total ~54.6 MB)

    k_zero <<<(NN + 255) / 256, 256, 0, stream>>>(cnt);
    k_count<<<(EE + 255) / 256, 256, 0, stream>>>(ei, cnt);
    k_r    <<<(NN + 255) / 256, 256, 0, stream>>>(cnt, r);
    k_scan1<<<NB_SCAN, 1024, 0, stream>>>(cnt, offs, bsum);
    k_scan2<<<1, 64, 0, stream>>>(bsum);
    k_scan3<<<NB_SCAN, 1024, 0, stream>>>(offs, bsum, cursor);
    k_fill <<<(EE + 255) / 256, 256, 0, stream>>>(ei, cursor, bucket);
    k_gemm <<<(NN + 127) / 128, 256, 0, stream>>>(x, W, b, h);
    k_gather<<<((size_t)NN * 64 + 255) / 256, 256, 0, stream>>>(bucket, offs, cursor, h, r, out);
}

// Round 6
// 223.183 us; speedup vs baseline: 5.1448x; 1.4518x over previous
//
#include <hip/hip_runtime.h>

#define NN 100000
#define EE 250000
#define DD 128
#define NB_SCAN 98   // ceil(NN/1024)

typedef __attribute__((ext_vector_type(8))) short short8v;   // 8 bf16 = 4 VGPR
typedef __attribute__((ext_vector_type(4))) float float4v;   // MFMA C/D

static __device__ __forceinline__ unsigned short f2bf(float f) {  // RNE fp32->bf16
    unsigned u = __builtin_bit_cast(unsigned, f);
    u += 0x7fff + ((u >> 16) & 1);
    return (unsigned short)(u >> 16);
}
static __device__ __forceinline__ float bf2f(unsigned short b) {
    unsigned u = ((unsigned)b) << 16;
    return __builtin_bit_cast(float, u);
}

// ---------------- CSR build ----------------
__global__ __launch_bounds__(256) void k_zero(int* __restrict__ cnt) {
    int i = blockIdx.x * 256 + threadIdx.x;
    if (i < NN) cnt[i] = 0;
}

__global__ __launch_bounds__(256) void k_count(const int* __restrict__ ei, int* __restrict__ cnt) {
    int e = blockIdx.x * 256 + threadIdx.x;
    if (e < EE) {
        atomicAdd(&cnt[ei[e]], 1);
        atomicAdd(&cnt[ei[EE + e]], 1);
    }
}

// scan1 also emits r = rsqrt(deg+1)  (deg>=1 -> reference clip is dead)
__global__ __launch_bounds__(1024) void k_scan1(const int* __restrict__ cnt,
                                                int* __restrict__ offs, int* __restrict__ bsum,
                                                float* __restrict__ r) {
    __shared__ int s[1024];
    int gid = blockIdx.x * 1024 + threadIdx.x;
    int v = (gid < NN) ? cnt[gid] : 0;
    if (gid < NN) r[gid] = rsqrtf((float)v + 1.0f);
    s[threadIdx.x] = v;
    __syncthreads();
    for (int d = 1; d < 1024; d <<= 1) {
        int t = (threadIdx.x >= d) ? s[threadIdx.x - d] : 0;
        __syncthreads();
        s[threadIdx.x] += t;
        __syncthreads();
    }
    if (gid < NN) offs[gid] = s[threadIdx.x] - v;   // exclusive
    if (threadIdx.x == 1023) bsum[blockIdx.x] = s[1023];
}

__global__ void k_scan2(int* __restrict__ bsum) {   // one wave, shuffle scan of 98 elems
    int l = threadIdx.x;   // 0..63
    int i0 = 2 * l, i1 = 2 * l + 1;
    int v0 = (i0 < NB_SCAN) ? bsum[i0] : 0;
    int v1 = (i1 < NB_SCAN) ? bsum[i1] : 0;
    int s = v0 + v1;
    for (int d = 1; d < 64; d <<= 1) {
        int t = __shfl_up(s, d);
        if (l >= d) s += t;
    }
    int excl = s - (v0 + v1);
    if (i0 < NB_SCAN) bsum[i0] = excl;
    if (i1 < NB_SCAN) bsum[i1] = excl + v0;
}

__global__ __launch_bounds__(1024) void k_scan3(int* __restrict__ offs, const int* __restrict__ bsum,
                                                int* __restrict__ cursor) {
    int gid = blockIdx.x * 1024 + threadIdx.x;
    if (gid < NN) {
        int o = offs[gid] + bsum[blockIdx.x];
        offs[gid] = o;
        cursor[gid] = o;
    }
}

__global__ __launch_bounds__(256) void k_fill(const int* __restrict__ ei,
                                              int* __restrict__ cursor, int* __restrict__ bucket) {
    int e = blockIdx.x * 256 + threadIdx.x;
    if (e < EE) {
        int u = ei[e], v = ei[EE + e];
        bucket[atomicAdd(&cursor[v], 1)] = u;
        bucket[atomicAdd(&cursor[u], 1)] = v;
    }
}

// ---------------- GEMM: hp = (x @ W^T + b) * r[row], split-bf16 MFMA ----------------
// 256 thr = 4 waves; wave w owns rows m0+w*32..+31 (2 m-frags), all 128 cols.
// W hi/lo staged in LDS (32KB each), XOR-swizzled: 16B-group kg stored at
// kg ^ (n&7) within row n  -> B-frag ds_read_b128 is bank-conflict-free (2-way).
// A-frags read straight from global x (8 contiguous fp32/lane, L1-resident).
// Split: Ahi*Bhi + Ahi*Blo + Alo*Bhi  (~2^-18 rel err, fp32-equivalent here).
__global__ __launch_bounds__(256) void k_gemm(const float* __restrict__ x,
                                              const float* __restrict__ W,
                                              const float* __restrict__ bias,
                                              const float* __restrict__ r,
                                              float* __restrict__ hp) {
    __shared__ unsigned short whi[DD * DD];   // 32 KB
    __shared__ unsigned short wlo[DD * DD];   // 32 KB
    const int t = threadIdx.x;

    // stage W: 2048 chunks of 8 floats -> 8 bf16 hi + 8 bf16 lo
    #pragma unroll
    for (int it = 0; it < 8; ++it) {
        int chunk = t + it * 256;            // 0..2047
        int n = chunk >> 4, kg = chunk & 15;
        const float4* Wv = (const float4*)W;
        float4 f0 = Wv[(size_t)chunk * 2];
        float4 f1 = Wv[(size_t)chunk * 2 + 1];
        float fs[8] = {f0.x, f0.y, f0.z, f0.w, f1.x, f1.y, f1.z, f1.w};
        int so = n * 128 + ((kg ^ (n & 7)) << 3);   // ushort index, 16B-swizzled
        short8v hi, lo;
        #pragma unroll
        for (int e = 0; e < 8; ++e) {
            unsigned short hb = f2bf(fs[e]);
            hi[e] = (short)hb;
            lo[e] = (short)f2bf(fs[e] - bf2f(hb));
        }
        *(short8v*)&whi[so] = hi;
        *(short8v*)&wlo[so] = lo;
    }
    __syncthreads();

    const int w = t >> 6, l = t & 63;
    const int lrow = l & 15, lkg = l >> 4;         // frag row/col, k-group
    const int m0 = blockIdx.x * 128 + w * 32;

    float4v acc[2][8];
    #pragma unroll
    for (int mf = 0; mf < 2; ++mf)
        #pragma unroll
        for (int j = 0; j < 8; ++j) acc[mf][j] = (float4v){0.f, 0.f, 0.f, 0.f};

    for (int k0 = 0; k0 < DD; k0 += 32) {
        short8v Ahi[2], Alo[2];
        #pragma unroll
        for (int mf = 0; mf < 2; ++mf) {
            int row = m0 + mf * 16 + lrow;
            float fs[8] = {0.f, 0.f, 0.f, 0.f, 0.f, 0.f, 0.f, 0.f};
            if (row < NN) {
                const float4* xr = (const float4*)(x + (size_t)row * DD + k0 + lkg * 8);
                float4 f0 = xr[0], f1 = xr[1];
                fs[0] = f0.x; fs[1] = f0.y; fs[2] = f0.z; fs[3] = f0.w;
                fs[4] = f1.x; fs[5] = f1.y; fs[6] = f1.z; fs[7] = f1.w;
            }
            #pragma unroll
            for (int e = 0; e < 8; ++e) {
                unsigned short hb = f2bf(fs[e]);
                Ahi[mf][e] = (short)hb;
                Alo[mf][e] = (short)f2bf(fs[e] - bf2f(hb));
            }
        }
        int kgf = (k0 >> 3) + lkg;
        #pragma unroll
        for (int j = 0; j < 8; ++j) {
            int n = 16 * j + lrow;
            int so = n * 128 + ((kgf ^ (n & 7)) << 3);
            short8v Bhi = *(const short8v*)&whi[so];
            short8v Blo = *(const short8v*)&wlo[so];
            #pragma unroll
            for (int mf = 0; mf < 2; ++mf) {
                acc[mf][j] = __builtin_amdgcn_mfma_f32_16x16x32_bf16(Ahi[mf], Bhi, acc[mf][j], 0, 0, 0);
                acc[mf][j] = __builtin_amdgcn_mfma_f32_16x16x32_bf16(Ahi[mf], Blo, acc[mf][j], 0, 0, 0);
                acc[mf][j] = __builtin_amdgcn_mfma_f32_16x16x32_bf16(Alo[mf], Bhi, acc[mf][j], 0, 0, 0);
            }
        }
    }

    // epilogue: hp[row][col] = (acc + bias[col]) * r[row]
    float bv[8];
    #pragma unroll
    for (int j = 0; j < 8; ++j) bv[j] = bias[16 * j + lrow];   // col = 16j + (l&15)
    #pragma unroll
    for (int mf = 0; mf < 2; ++mf)
        #pragma unroll
        for (int reg = 0; reg < 4; ++reg) {
            int row = m0 + mf * 16 + (l >> 4) * 4 + reg;       // C/D: row=(lane>>4)*4+reg
            if (row < NN) {
                float rr = r[row];
                #pragma unroll
                for (int j = 0; j < 8; ++j) {
                    int col = 16 * j + lrow;                    // C/D: col=lane&15
                    hp[(size_t)row * DD + col] = (acc[mf][j][reg] + bv[j]) * rr;
                }
            }
        }
}

// ---------------- gather: out[n] = r[n] * (hp[n] + sum_{s in adj(n)} hp[s]) ----------------
__global__ __launch_bounds__(256) void k_gather(const int* __restrict__ bucket,
                                                const int* __restrict__ offs,
                                                const int* __restrict__ cursor,
                                                const float* __restrict__ hp,
                                                const float* __restrict__ r,
                                                float* __restrict__ out) {
    int wid  = (blockIdx.x * 256 + threadIdx.x) >> 6;
    int lane = threadIdx.x & 63;
    if (wid >= NN) return;
    const int start = offs[wid];
    const int end   = cursor[wid];           // offs + deg after fill
    float2 acc = ((const float2*)(hp + (size_t)wid * DD))[lane];   // self loop
    int j = start;
    for (; j + 1 < end; j += 2) {            // 2 independent row-loads in flight
        int s0 = bucket[j], s1 = bucket[j + 1];
        float2 a0 = ((const float2*)(hp + (size_t)s0 * DD))[lane];
        float2 a1 = ((const float2*)(hp + (size_t)s1 * DD))[lane];
        acc.x += a0.x + a1.x;
        acc.y += a0.y + a1.y;
    }
    if (j < end) {
        int s = bucket[j];
        float2 a = ((const float2*)(hp + (size_t)s * DD))[lane];
        acc.x += a.x;
        acc.y += a.y;
    }
    float rd = r[wid];
    ((float2*)(out + (size_t)wid * DD))[lane] = make_float2(acc.x * rd, acc.y * rd);
}

extern "C" void kernel_launch(void* const* d_in, const int* in_sizes, int n_in,
                              void* d_out, int out_size, void* d_ws, size_t ws_size,
                              hipStream_t stream) {
    const float* x  = (const float*)d_in[0];
    const int*   ei = (const int*)d_in[1];
    const float* W  = (const float*)d_in[2];
    const float* b  = (const float*)d_in[3];
    float* out = (float*)d_out;

    float* hp     = (float*)d_ws;                       // N*128 fp32 = 51.2 MB
    float* r      = hp + (size_t)NN * DD;               // 100k
    int*   cnt    = (int*)(r + NN);                     // 100k
    int*   offs   = cnt + NN;                           // 100k
    int*   cursor = offs + NN;                          // 100k
    int*   bsum   = cursor + NN;                        // 128
    int*   bucket = bsum + 128;                         // 500k

    k_zero <<<(NN + 255) / 256, 256, 0, stream>>>(cnt);
    k_count<<<(EE + 255) / 256, 256, 0, stream>>>(ei, cnt);
    k_scan1<<<NB_SCAN, 1024, 0, stream>>>(cnt, offs, bsum, r);
    k_scan2<<<1, 64, 0, stream>>>(bsum);
    k_scan3<<<NB_SCAN, 1024, 0, stream>>>(offs, bsum, cursor);
    k_fill <<<(EE + 255) / 256, 256, 0, stream>>>(ei, cursor, bucket);
    k_gemm <<<(NN + 127) / 128, 256, 0, stream>>>(x, W, b, r, hp);
    k_gather<<<((size_t)NN * 64 + 255) / 256, 256, 0, stream>>>(bucket, offs, cursor, hp, r, out);
}

// Round 8
// 213.831 us; speedup vs baseline: 5.3698x; 1.0437x over previous
//
#include <hip/hip_runtime.h>
#include <hip/hip_fp16.h>

#define NN 100000
#define EE 250000
#define DD 128
#define NB_SCAN 98   // ceil(NN/1024)

typedef __attribute__((ext_vector_type(8))) short short8v;   // 8 bf16 = 4 VGPR
typedef __attribute__((ext_vector_type(4))) float float4v;   // MFMA C/D

static __device__ __forceinline__ unsigned short f2bf(float f) {  // RNE fp32->bf16
    unsigned u = __builtin_bit_cast(unsigned, f);
    u += 0x7fff + ((u >> 16) & 1);
    return (unsigned short)(u >> 16);
}
static __device__ __forceinline__ float bf2f(unsigned short b) {
    unsigned u = ((unsigned)b) << 16;
    return __builtin_bit_cast(float, u);
}

// ---------------- CSR build ----------------
__global__ __launch_bounds__(256) void k_zero(int* __restrict__ cnt) {
    int i = blockIdx.x * 256 + threadIdx.x;
    if (i < NN) cnt[i] = 0;
}

__global__ __launch_bounds__(256) void k_count(const int* __restrict__ ei, int* __restrict__ cnt) {
    int e = blockIdx.x * 256 + threadIdx.x;
    if (e < EE) {
        atomicAdd(&cnt[ei[e]], 1);
        atomicAdd(&cnt[ei[EE + e]], 1);
    }
}

// scan1 also emits r = rsqrt(deg+1)  (deg>=1 -> reference clip is dead)
__global__ __launch_bounds__(1024) void k_scan1(const int* __restrict__ cnt,
                                                int* __restrict__ offs, int* __restrict__ bsum,
                                                float* __restrict__ r) {
    __shared__ int s[1024];
    int gid = blockIdx.x * 1024 + threadIdx.x;
    int v = (gid < NN) ? cnt[gid] : 0;
    if (gid < NN) r[gid] = rsqrtf((float)v + 1.0f);
    s[threadIdx.x] = v;
    __syncthreads();
    for (int d = 1; d < 1024; d <<= 1) {
        int t = (threadIdx.x >= d) ? s[threadIdx.x - d] : 0;
        __syncthreads();
        s[threadIdx.x] += t;
        __syncthreads();
    }
    if (gid < NN) offs[gid] = s[threadIdx.x] - v;   // exclusive
    if (threadIdx.x == 1023) bsum[blockIdx.x] = s[1023];
}

__global__ void k_scan2(int* __restrict__ bsum) {   // one wave, shuffle scan of 98 elems
    int l = threadIdx.x;   // 0..63
    int i0 = 2 * l, i1 = 2 * l + 1;
    int v0 = (i0 < NB_SCAN) ? bsum[i0] : 0;
    int v1 = (i1 < NB_SCAN) ? bsum[i1] : 0;
    int s = v0 + v1;
    for (int d = 1; d < 64; d <<= 1) {
        int t = __shfl_up(s, d);
        if (l >= d) s += t;
    }
    int excl = s - (v0 + v1);
    if (i0 < NB_SCAN) bsum[i0] = excl;
    if (i1 < NB_SCAN) bsum[i1] = excl + v0;
}

__global__ __launch_bounds__(1024) void k_scan3(int* __restrict__ offs, const int* __restrict__ bsum,
                                                int* __restrict__ cursor) {
    int gid = blockIdx.x * 1024 + threadIdx.x;
    if (gid < NN) {
        int o = offs[gid] + bsum[blockIdx.x];
        offs[gid] = o;
        cursor[gid] = o;
    }
}

__global__ __launch_bounds__(256) void k_fill(const int* __restrict__ ei,
                                              int* __restrict__ cursor, int* __restrict__ bucket) {
    int e = blockIdx.x * 256 + threadIdx.x;
    if (e < EE) {
        int u = ei[e], v = ei[EE + e];
        bucket[atomicAdd(&cursor[v], 1)] = u;
        bucket[atomicAdd(&cursor[u], 1)] = v;
    }
}

// ---------------- GEMM: hp = fp16( (x @ W^T + b) * r[row] ), split-bf16 MFMA ----------------
// Same structure as round 6 (verified): W hi/lo XOR-swizzled in 64KB LDS,
// A-frags straight from global, Ahi*Bhi + Ahi*Blo + Alo*Bhi.
// Epilogue now stores fp16 -> halves the random-gather row size downstream.
__global__ __launch_bounds__(256) void k_gemm(const float* __restrict__ x,
                                              const float* __restrict__ W,
                                              const float* __restrict__ bias,
                                              const float* __restrict__ r,
                                              __half* __restrict__ hp) {
    __shared__ unsigned short whi[DD * DD];   // 32 KB
    __shared__ unsigned short wlo[DD * DD];   // 32 KB
    const int t = threadIdx.x;

    #pragma unroll
    for (int it = 0; it < 8; ++it) {
        int chunk = t + it * 256;            // 0..2047
        int n = chunk >> 4, kg = chunk & 15;
        const float4* Wv = (const float4*)W;
        float4 f0 = Wv[(size_t)chunk * 2];
        float4 f1 = Wv[(size_t)chunk * 2 + 1];
        float fs[8] = {f0.x, f0.y, f0.z, f0.w, f1.x, f1.y, f1.z, f1.w};
        int so = n * 128 + ((kg ^ (n & 7)) << 3);   // ushort index, 16B-swizzled
        short8v hi, lo;
        #pragma unroll
        for (int e = 0; e < 8; ++e) {
            unsigned short hb = f2bf(fs[e]);
            hi[e] = (short)hb;
            lo[e] = (short)f2bf(fs[e] - bf2f(hb));
        }
        *(short8v*)&whi[so] = hi;
        *(short8v*)&wlo[so] = lo;
    }
    __syncthreads();

    const int w = t >> 6, l = t & 63;
    const int lrow = l & 15, lkg = l >> 4;
    const int m0 = blockIdx.x * 128 + w * 32;

    float4v acc[2][8];
    #pragma unroll
    for (int mf = 0; mf < 2; ++mf)
        #pragma unroll
        for (int j = 0; j < 8; ++j) acc[mf][j] = (float4v){0.f, 0.f, 0.f, 0.f};

    for (int k0 = 0; k0 < DD; k0 += 32) {
        short8v Ahi[2], Alo[2];
        #pragma unroll
        for (int mf = 0; mf < 2; ++mf) {
            int row = m0 + mf * 16 + lrow;
            float fs[8] = {0.f, 0.f, 0.f, 0.f, 0.f, 0.f, 0.f, 0.f};
            if (row < NN) {
                const float4* xr = (const float4*)(x + (size_t)row * DD + k0 + lkg * 8);
                float4 f0 = xr[0], f1 = xr[1];
                fs[0] = f0.x; fs[1] = f0.y; fs[2] = f0.z; fs[3] = f0.w;
                fs[4] = f1.x; fs[5] = f1.y; fs[6] = f1.z; fs[7] = f1.w;
            }
            #pragma unroll
            for (int e = 0; e < 8; ++e) {
                unsigned short hb = f2bf(fs[e]);
                Ahi[mf][e] = (short)hb;
                Alo[mf][e] = (short)f2bf(fs[e] - bf2f(hb));
            }
        }
        int kgf = (k0 >> 3) + lkg;
        #pragma unroll
        for (int j = 0; j < 8; ++j) {
            int n = 16 * j + lrow;
            int so = n * 128 + ((kgf ^ (n & 7)) << 3);
            short8v Bhi = *(const short8v*)&whi[so];
            short8v Blo = *(const short8v*)&wlo[so];
            #pragma unroll
            for (int mf = 0; mf < 2; ++mf) {
                acc[mf][j] = __builtin_amdgcn_mfma_f32_16x16x32_bf16(Ahi[mf], Bhi, acc[mf][j], 0, 0, 0);
                acc[mf][j] = __builtin_amdgcn_mfma_f32_16x16x32_bf16(Ahi[mf], Blo, acc[mf][j], 0, 0, 0);
                acc[mf][j] = __builtin_amdgcn_mfma_f32_16x16x32_bf16(Alo[mf], Bhi, acc[mf][j], 0, 0, 0);
            }
        }
    }

    float bv[8];
    #pragma unroll
    for (int j = 0; j < 8; ++j) bv[j] = bias[16 * j + lrow];   // col = 16j + (l&15)
    #pragma unroll
    for (int mf = 0; mf < 2; ++mf)
        #pragma unroll
        for (int reg = 0; reg < 4; ++reg) {
            int row = m0 + mf * 16 + (l >> 4) * 4 + reg;       // C/D: row=(lane>>4)*4+reg
            if (row < NN) {
                float rr = r[row];
                #pragma unroll
                for (int j = 0; j < 8; ++j) {
                    int col = 16 * j + lrow;                    // C/D: col=lane&15
                    hp[(size_t)row * DD + col] = __float2half((acc[mf][j][reg] + bv[j]) * rr);
                }
            }
        }
}

// ---------------- gather: out[n] = r[n] * (hp[n] + sum_{s in adj(n)} hp[s]) ----------------
// hp is fp16: 256 B per gathered row (halves the BW-bound random-fetch volume).
__global__ __launch_bounds__(256) void k_gather(const int* __restrict__ bucket,
                                                const int* __restrict__ offs,
                                                const int* __restrict__ cursor,
                                                const __half* __restrict__ hp,
                                                const float* __restrict__ r,
                                                float* __restrict__ out) {
    int wid  = (blockIdx.x * 256 + threadIdx.x) >> 6;
    int lane = threadIdx.x & 63;
    if (wid >= NN) return;
    const int start = offs[wid];
    const int end   = cursor[wid];           // offs + deg after fill
    float2 acc = __half22float2(((const __half2*)(hp + (size_t)wid * DD))[lane]);   // self loop
    int j = start;
    for (; j + 1 < end; j += 2) {            // 2 independent row-loads in flight
        int s0 = bucket[j], s1 = bucket[j + 1];
        float2 a0 = __half22float2(((const __half2*)(hp + (size_t)s0 * DD))[lane]);
        float2 a1 = __half22float2(((const __half2*)(hp + (size_t)s1 * DD))[lane]);
        acc.x += a0.x + a1.x;
        acc.y += a0.y + a1.y;
    }
    if (j < end) {
        int s = bucket[j];
        float2 a = __half22float2(((const __half2*)(hp + (size_t)s * DD))[lane]);
        acc.x += a.x;
        acc.y += a.y;
    }
    float rd = r[wid];
    float2 res = make_float2(acc.x * rd, acc.y * rd);
    // out written once, never re-read -> non-temporal (don't evict hp/bucket from L2)
    __builtin_nontemporal_store(__builtin_bit_cast(double, res),
                                (double*)(out + (size_t)wid * DD + lane * 2));
}

extern "C" void kernel_launch(void* const* d_in, const int* in_sizes, int n_in,
                              void* d_out, int out_size, void* d_ws, size_t ws_size,
                              hipStream_t stream) {
    const float* x  = (const float*)d_in[0];
    const int*   ei = (const int*)d_in[1];
    const float* W  = (const float*)d_in[2];
    const float* b  = (const float*)d_in[3];
    float* out = (float*)d_out;

    __half* hp    = (__half*)d_ws;                      // N*128 fp16 = 25.6 MB
    float*  r     = (float*)(hp + (size_t)NN * DD);     // 100k
    int*   cnt    = (int*)(r + NN);                     // 100k
    int*   offs   = cnt + NN;                           // 100k
    int*   cursor = offs + NN;                          // 100k
    int*   bsum   = cursor + NN;                        // 128
    int*   bucket = bsum + 128;                         // 500k

    k_zero <<<(NN + 255) / 256, 256, 0, stream>>>(cnt);
    k_count<<<(EE + 255) / 256, 256, 0, stream>>>(ei, cnt);
    k_scan1<<<NB_SCAN, 1024, 0, stream>>>(cnt, offs, bsum, r);
    k_scan2<<<1, 64, 0, stream>>>(bsum);
    k_scan3<<<NB_SCAN, 1024, 0, stream>>>(offs, bsum, cursor);
    k_fill <<<(EE + 255) / 256, 256, 0, stream>>>(ei, cursor, bucket);
    k_gemm <<<(NN + 127) / 128, 256, 0, stream>>>(x, W, b, r, hp);
    k_gather<<<((size_t)NN * 64 + 255) / 256, 256, 0, stream>>>(bucket, offs, cursor, hp, r, out);
}